// Round 9
// baseline (1209.444 us; speedup 1.0000x reference)
//
#include <hip/hip_runtime.h>

#define N_NODES 100000
#define N_EDGES 1600000
#define IN_DIM 256
#define OUT_DIM 128
#define BROWS 100          // rows per bucket
#define NBK 1000           // buckets (100000/100 exactly)
#define PBLK 128           // partition blocks
#define EPB 12500          // edges per partition block (1.6M/128)

typedef __attribute__((ext_vector_type(4))) float f32x4;
typedef __attribute__((ext_vector_type(8))) short s16x8;

__device__ inline unsigned short f2bf(float f) {
    union { float f; unsigned int u; } a; a.f = f;
    unsigned int r = a.u + 0x7fffu + ((a.u >> 16) & 1u);
    return (unsigned short)(r >> 16);
}
__device__ inline float bf2f(unsigned short h) {
    union { unsigned int u; float f; } a; a.u = ((unsigned int)h) << 16;
    return a.f;
}

// ---------------- Kernel 0: u = fsW @ wi, v = fsW @ wj ----------------
__global__ void kuv(const float* __restrict__ fsW, const float* __restrict__ fw,
                    float* __restrict__ u, float* __restrict__ v) {
    __shared__ float wi[128], wj[128];
    int t = threadIdx.x;
    if (t < 128) wi[t] = fw[t]; else wj[t - 128] = fw[t];
    __syncthreads();
    const float* rowp = fsW + (size_t)t * OUT_DIM;
    float su = 0.f, sv = 0.f;
    for (int d = 0; d < 128; d += 4) {
        float4 a = *(const float4*)(rowp + d);
        su += a.x * wi[d] + a.y * wi[d + 1] + a.z * wi[d + 2] + a.w * wi[d + 3];
        sv += a.x * wj[d] + a.y * wj[d + 1] + a.z * wj[d + 2] + a.w * wj[d + 3];
    }
    u[t] = su; v[t] = sv;
}

// ---------------- Kernel 0b: wt[n][k] = bf16(W[k][n])  (128 x 256) ----------------
__global__ void kwt(const float* __restrict__ W, unsigned short* __restrict__ wt) {
    int n = blockIdx.x;
    int k = threadIdx.x;
    wt[n * 256 + k] = f2bf(W[(size_t)k * 128 + n]);
}

// ------- Kernel 1: pre_sup(bf16) = x@W via MFMA ; si = x.u ; sj = x.v -------
__global__ __launch_bounds__(256) void gemm_mfma(
        const float* __restrict__ x, const unsigned short* __restrict__ wt,
        const float* __restrict__ u, const float* __restrict__ v,
        unsigned short* __restrict__ psb, float* __restrict__ si, float* __restrict__ sj) {
    __shared__ unsigned short xa[64 * 136];
    __shared__ unsigned short wb[128 * 136];

    const int t = threadIdx.x;
    const int wave = t >> 6, lane = t & 63;
    const int l15 = lane & 15, lhi = lane >> 4;
    const int row = t >> 2, quad = t & 3;
    const int brow = blockIdx.x * 64;
    const int gnode = brow + row;
    const bool valid = gnode < N_NODES;

    f32x4 acc[4][2];
#pragma unroll
    for (int mi = 0; mi < 4; ++mi)
#pragma unroll
        for (int ni = 0; ni < 2; ++ni) acc[mi][ni] = (f32x4){0.f, 0.f, 0.f, 0.f};
    float su = 0.f, sv = 0.f;

#pragma unroll
    for (int ph = 0; ph < 2; ++ph) {
        {
            const float* xp = x + (size_t)gnode * IN_DIM + ph * 128 + quad * 32;
            const float* up = u + ph * 128 + quad * 32;
            const float* vp = v + ph * 128 + quad * 32;
#pragma unroll
            for (int cc = 0; cc < 4; ++cc) {
                float4 a0 = make_float4(0.f, 0.f, 0.f, 0.f), a1 = a0;
                if (valid) {
                    a0 = ((const float4*)xp)[cc * 2];
                    a1 = ((const float4*)xp)[cc * 2 + 1];
                    float4 u0 = ((const float4*)up)[cc * 2], u1 = ((const float4*)up)[cc * 2 + 1];
                    float4 v0 = ((const float4*)vp)[cc * 2], v1 = ((const float4*)vp)[cc * 2 + 1];
                    su = fmaf(a0.x, u0.x, su); su = fmaf(a0.y, u0.y, su);
                    su = fmaf(a0.z, u0.z, su); su = fmaf(a0.w, u0.w, su);
                    su = fmaf(a1.x, u1.x, su); su = fmaf(a1.y, u1.y, su);
                    su = fmaf(a1.z, u1.z, su); su = fmaf(a1.w, u1.w, su);
                    sv = fmaf(a0.x, v0.x, sv); sv = fmaf(a0.y, v0.y, sv);
                    sv = fmaf(a0.z, v0.z, sv); sv = fmaf(a0.w, v0.w, sv);
                    sv = fmaf(a1.x, v1.x, sv); sv = fmaf(a1.y, v1.y, sv);
                    sv = fmaf(a1.z, v1.z, sv); sv = fmaf(a1.w, v1.w, sv);
                }
                union { unsigned short h[8]; uint4 q; } pk;
                pk.h[0] = f2bf(a0.x); pk.h[1] = f2bf(a0.y); pk.h[2] = f2bf(a0.z); pk.h[3] = f2bf(a0.w);
                pk.h[4] = f2bf(a1.x); pk.h[5] = f2bf(a1.y); pk.h[6] = f2bf(a1.z); pk.h[7] = f2bf(a1.w);
                *(uint4*)&xa[row * 136 + quad * 32 + cc * 8] = pk.q;
            }
        }
        {
            const int wrow = t >> 1, half = t & 1;
            const unsigned short* wp = wt + (size_t)wrow * 256 + ph * 128 + half * 64;
#pragma unroll
            for (int c = 0; c < 8; ++c)
                *(uint4*)&wb[wrow * 136 + half * 64 + c * 8] = ((const uint4*)wp)[c];
        }
        __syncthreads();

#pragma unroll
        for (int ks = 0; ks < 4; ++ks) {
            const int k0 = ks * 32 + lhi * 8;
            s16x8 afr[4], bfr[2];
#pragma unroll
            for (int mi = 0; mi < 4; ++mi)
                afr[mi] = *(const s16x8*)&xa[(mi * 16 + l15) * 136 + k0];
#pragma unroll
            for (int ni = 0; ni < 2; ++ni)
                bfr[ni] = *(const s16x8*)&wb[(wave * 32 + ni * 16 + l15) * 136 + k0];
#pragma unroll
            for (int mi = 0; mi < 4; ++mi)
#pragma unroll
                for (int ni = 0; ni < 2; ++ni)
                    acc[mi][ni] = __builtin_amdgcn_mfma_f32_16x16x32_bf16(
                        afr[mi], bfr[ni], acc[mi][ni], 0, 0, 0);
        }
        __syncthreads();
    }

    su += __shfl_xor(su, 1); su += __shfl_xor(su, 2);
    sv += __shfl_xor(sv, 1); sv += __shfl_xor(sv, 2);
    if (quad == 0 && valid) { si[gnode] = su; sj[gnode] = sv; }

#pragma unroll
    for (int mi = 0; mi < 4; ++mi) {
        int node = brow + mi * 16 + lhi * 4;
#pragma unroll
        for (int ni = 0; ni < 2; ++ni) {
            int colb = wave * 32 + ni * 16 + l15;
#pragma unroll
            for (int j = 0; j < 4; ++j) {
                if (node + j < N_NODES)
                    psb[(size_t)(node + j) * OUT_DIM + colb] = f2bf(acc[mi][ni][j]);
            }
        }
    }
}

// ------- Kernel 2: per-(block,bucket) histogram -------
__global__ __launch_bounds__(256) void khist1(const int* __restrict__ row,
                                              int* __restrict__ hist_t) {
    __shared__ int h[NBK];
    const int t = threadIdx.x, blk = blockIdx.x;
    for (int b = t; b < NBK; b += 256) h[b] = 0;
    __syncthreads();
    const int e0 = blk * EPB;
    for (int i = t; i < EPB; i += 256) {
        int r = row[e0 + i];
        atomicAdd(&h[r / BROWS], 1);
    }
    __syncthreads();
    for (int b = t; b < NBK; b += 256)
        hist_t[b * PBLK + blk] = h[b];
}

// ------- Kernel 3: bucket sums + exclusive scan (single block) -------
__global__ __launch_bounds__(1024) void kbscan(const int* __restrict__ hist_t,
                                               int* __restrict__ bpre) {
    __shared__ int s[1024];
    const int t = threadIdx.x;
    int v = 0;
    if (t < NBK) {
        const int* hp = hist_t + t * PBLK;
        for (int k = 0; k < PBLK; ++k) v += hp[k];
    }
    s[t] = v;
    __syncthreads();
    for (int off = 1; off < 1024; off <<= 1) {
        int nv = (t >= off) ? s[t - off] : 0;
        __syncthreads();
        s[t] += nv;
        __syncthreads();
    }
    if (t < NBK) bpre[t] = s[t] - v;
    if (t == 1023) bpre[NBK] = s[1023];
}

// ------- Kernel 4: per-(bucket,block) offsets -------
__global__ __launch_bounds__(128) void koff(const int* __restrict__ hist_t,
                                            const int* __restrict__ bpre,
                                            int* __restrict__ off) {
    const int b = blockIdx.x, t = threadIdx.x;
    const int lane = t & 63, w = t >> 6;
    int v = hist_t[b * PBLK + t];
    int s = v;
#pragma unroll
    for (int o = 1; o < 64; o <<= 1) { int tt = __shfl_up(s, o); if (lane >= o) s += tt; }
    __shared__ int ws2[2];
    if (lane == 63) ws2[w] = s;
    __syncthreads();
    int base = (w == 1) ? ws2[0] : 0;
    off[b * PBLK + t] = bpre[b] + base + (s - v);
}

// ------- Kernel 5: partition edges into bucket sub-segments (packed 4B) -------
__global__ __launch_bounds__(256) void kpart(const int* __restrict__ row,
                                             const int* __restrict__ col,
                                             const int* __restrict__ off,
                                             unsigned int* __restrict__ part) {
    __shared__ int cur[NBK];
    const int t = threadIdx.x, blk = blockIdx.x;
    for (int b = t; b < NBK; b += 256) cur[b] = off[b * PBLK + blk];
    __syncthreads();
    const int e0 = blk * EPB;
    for (int i = t; i < EPB; i += 256) {
        int r = row[e0 + i], c = col[e0 + i];
        int b = r / BROWS;
        int rl = r - b * BROWS;
        int pos = atomicAdd(&cur[b], 1);
        part[pos] = ((unsigned)rl << 17) | (unsigned)c;
    }
}

// ------- Kernel 6: per-bucket aggregation in LDS + ReLU + coalesced out -------
// acc[rl][d]; lane l owns dims {l, l+32, l+64, l+96} -> ds_add banks all distinct.
__global__ __launch_bounds__(256) void kagg(
        const unsigned int* __restrict__ part, const int* __restrict__ bpre,
        const float* __restrict__ si, const float* __restrict__ sj,
        const float* __restrict__ dia, const float* __restrict__ fb,
        const unsigned short* __restrict__ psb, float* __restrict__ out) {
    __shared__ float acc[BROWS * 128];       // 51200 B
    __shared__ float vtile[256];
    __shared__ unsigned int pktile[256];

    const int t = threadIdx.x;
    const int b = blockIdx.x;
    const int rbase = b * BROWS;
    const float fbv = fb[0];

    for (int i = t * 4; i < BROWS * 128; i += 1024)
        *(float4*)&acc[i] = make_float4(0.f, 0.f, 0.f, 0.f);
    __syncthreads();

    const int bstart = bpre[b], bend = bpre[b + 1];
    const int lane = t & 31, grp = t >> 5;

    for (int tb = bstart; tb < bend; tb += 256) {
        // phase A: one edge per thread -> val + packed (rl,c)
        int e = tb + t;
        if (e < bend) {
            unsigned int pk = part[e];
            int rl = (int)(pk >> 17);
            int c  = (int)(pk & 0x1FFFFu);
            int r  = rbase + rl;
            float tval = si[r] + sj[c] + fbv;
            float sg = 1.f / (1.f + expf(-tval));
            float l2 = log2f(dia[r] * dia[c]);
            vtile[t] = exp2f(-sg * l2);
            pktile[t] = pk;
        }
        __syncthreads();
        // phase B: 8 groups of 32 lanes; group g handles edges g, g+8, ...
        int cnt = bend - tb; if (cnt > 256) cnt = 256;
        for (int i = grp; i < cnt; i += 8) {
            unsigned int pk = pktile[i];
            int rl = (int)(pk >> 17);
            int c  = (int)(pk & 0x1FFFFu);
            float vv = vtile[i];
            const unsigned short* prow = psb + (size_t)c * OUT_DIM;
            float p0 = bf2f(prow[lane]);
            float p1 = bf2f(prow[lane + 32]);
            float p2 = bf2f(prow[lane + 64]);
            float p3 = bf2f(prow[lane + 96]);
            float* arow = &acc[rl * 128 + lane];
            atomicAdd(&arow[0],  vv * p0);
            atomicAdd(&arow[32], vv * p1);
            atomicAdd(&arow[64], vv * p2);
            atomicAdd(&arow[96], vv * p3);
        }
        __syncthreads();
    }

    // epilogue: ReLU + coalesced write (buckets tile N_NODES exactly)
    for (int i = t * 4; i < BROWS * 128; i += 1024) {
        int r = rbase + (i >> 7);
        int d = i & 127;
        float4 a = *(float4*)&acc[i];
        float4 o;
        o.x = fmaxf(a.x, 0.f); o.y = fmaxf(a.y, 0.f);
        o.z = fmaxf(a.z, 0.f); o.w = fmaxf(a.w, 0.f);
        *(float4*)&out[(size_t)r * OUT_DIM + d] = o;
    }
}

extern "C" void kernel_launch(void* const* d_in, const int* in_sizes, int n_in,
                              void* d_out, int out_size, void* d_ws, size_t ws_size,
                              hipStream_t stream) {
    const float* x   = (const float*)d_in[0];
    const float* W   = (const float*)d_in[1];
    const float* fsW = (const float*)d_in[2];
    const float* fw  = (const float*)d_in[3];
    const float* fb  = (const float*)d_in[4];
    const float* dia = (const float*)d_in[5];
    const int*   row = (const int*)d_in[6];
    const int*   col = (const int*)d_in[7];
    float* out = (float*)d_out;

    char* p = (char*)d_ws;
    auto alloc = [&](size_t bytes) -> char* {
        char* r = p; p += (bytes + 255) & ~(size_t)255; return r;
    };
    float* u      = (float*)alloc(256 * 4);
    float* v      = (float*)alloc(256 * 4);
    unsigned short* wtb = (unsigned short*)alloc((size_t)128 * 256 * 2);
    float* si     = (float*)alloc((size_t)N_NODES * 4);
    float* sj     = (float*)alloc((size_t)N_NODES * 4);
    unsigned short* psb = (unsigned short*)alloc((size_t)N_NODES * OUT_DIM * 2);
    int*   hist_t = (int*)alloc((size_t)NBK * PBLK * 4);
    int*   bpre   = (int*)alloc((size_t)(NBK + 1) * 4);
    int*   off    = (int*)alloc((size_t)NBK * PBLK * 4);
    unsigned int* part = (unsigned int*)alloc((size_t)N_EDGES * 4);

    kuv<<<1, 256, 0, stream>>>(fsW, fw, u, v);
    kwt<<<128, 256, 0, stream>>>(W, wtb);
    gemm_mfma<<<(N_NODES + 63) / 64, 256, 0, stream>>>(x, wtb, u, v, psb, si, sj);
    khist1<<<PBLK, 256, 0, stream>>>(row, hist_t);
    kbscan<<<1, 1024, 0, stream>>>(hist_t, bpre);
    koff<<<NBK, PBLK, 0, stream>>>(hist_t, bpre, off);
    kpart<<<PBLK, 256, 0, stream>>>(row, col, off, part);
    kagg<<<NBK, 256, 0, stream>>>(part, bpre, si, sj, dia, fb, psb, out);
}

// Round 10
// 277.902 us; speedup vs baseline: 4.3520x; 4.3520x over previous
//
#include <hip/hip_runtime.h>

#define N_NODES 100000
#define N_EDGES 1600000
#define IN_DIM 256
#define OUT_DIM 128
#define SCAN_B 1024
#define SCAN_NB 98   // ceil(100000/1024)
#define BROWS 100    // rows per bucket
#define NBK 1000     // buckets
#define PBLK 128     // partition blocks
#define EPB 12500    // edges per partition block

typedef __attribute__((ext_vector_type(4))) float f32x4;
typedef __attribute__((ext_vector_type(8))) short s16x8;

__device__ inline unsigned short f2bf(float f) {
    union { float f; unsigned int u; } a; a.f = f;
    unsigned int r = a.u + 0x7fffu + ((a.u >> 16) & 1u);
    return (unsigned short)(r >> 16);
}
__device__ inline float bf2f(unsigned short h) {
    union { unsigned int u; float f; } a; a.u = ((unsigned int)h) << 16;
    return a.f;
}

// ---------------- Kernel 0: u = fsW @ wi, v = fsW @ wj ----------------
__global__ void kuv(const float* __restrict__ fsW, const float* __restrict__ fw,
                    float* __restrict__ u, float* __restrict__ v) {
    __shared__ float wi[128], wj[128];
    int t = threadIdx.x;
    if (t < 128) wi[t] = fw[t]; else wj[t - 128] = fw[t];
    __syncthreads();
    const float* rowp = fsW + (size_t)t * OUT_DIM;
    float su = 0.f, sv = 0.f;
    for (int d = 0; d < 128; d += 4) {
        float4 a = *(const float4*)(rowp + d);
        su += a.x * wi[d] + a.y * wi[d + 1] + a.z * wi[d + 2] + a.w * wi[d + 3];
        sv += a.x * wj[d] + a.y * wj[d + 1] + a.z * wj[d + 2] + a.w * wj[d + 3];
    }
    u[t] = su; v[t] = sv;
}

// ---------------- Kernel 0b: wt[n][k] = bf16(W[k][n]) ----------------
__global__ void kwt(const float* __restrict__ W, unsigned short* __restrict__ wt) {
    int n = blockIdx.x;
    int k = threadIdx.x;
    wt[n * 256 + k] = f2bf(W[(size_t)k * 128 + n]);
}

// ------- Kernel 1: pre_sup(bf16) = x@W via MFMA ; si = x.u ; sj = x.v -------
__global__ __launch_bounds__(256) void gemm_mfma(
        const float* __restrict__ x, const unsigned short* __restrict__ wt,
        const float* __restrict__ u, const float* __restrict__ v,
        unsigned short* __restrict__ psb, float* __restrict__ si, float* __restrict__ sj) {
    __shared__ unsigned short xa[64 * 136];
    __shared__ unsigned short wb[128 * 136];

    const int t = threadIdx.x;
    const int wave = t >> 6, lane = t & 63;
    const int l15 = lane & 15, lhi = lane >> 4;
    const int row = t >> 2, quad = t & 3;
    const int brow = blockIdx.x * 64;
    const int gnode = brow + row;
    const bool valid = gnode < N_NODES;

    f32x4 acc[4][2];
#pragma unroll
    for (int mi = 0; mi < 4; ++mi)
#pragma unroll
        for (int ni = 0; ni < 2; ++ni) acc[mi][ni] = (f32x4){0.f, 0.f, 0.f, 0.f};
    float su = 0.f, sv = 0.f;

#pragma unroll
    for (int ph = 0; ph < 2; ++ph) {
        {
            const float* xp = x + (size_t)gnode * IN_DIM + ph * 128 + quad * 32;
            const float* up = u + ph * 128 + quad * 32;
            const float* vp = v + ph * 128 + quad * 32;
#pragma unroll
            for (int cc = 0; cc < 4; ++cc) {
                float4 a0 = make_float4(0.f, 0.f, 0.f, 0.f), a1 = a0;
                if (valid) {
                    a0 = ((const float4*)xp)[cc * 2];
                    a1 = ((const float4*)xp)[cc * 2 + 1];
                    float4 u0 = ((const float4*)up)[cc * 2], u1 = ((const float4*)up)[cc * 2 + 1];
                    float4 v0 = ((const float4*)vp)[cc * 2], v1 = ((const float4*)vp)[cc * 2 + 1];
                    su = fmaf(a0.x, u0.x, su); su = fmaf(a0.y, u0.y, su);
                    su = fmaf(a0.z, u0.z, su); su = fmaf(a0.w, u0.w, su);
                    su = fmaf(a1.x, u1.x, su); su = fmaf(a1.y, u1.y, su);
                    su = fmaf(a1.z, u1.z, su); su = fmaf(a1.w, u1.w, su);
                    sv = fmaf(a0.x, v0.x, sv); sv = fmaf(a0.y, v0.y, sv);
                    sv = fmaf(a0.z, v0.z, sv); sv = fmaf(a0.w, v0.w, sv);
                    sv = fmaf(a1.x, v1.x, sv); sv = fmaf(a1.y, v1.y, sv);
                    sv = fmaf(a1.z, v1.z, sv); sv = fmaf(a1.w, v1.w, sv);
                }
                union { unsigned short h[8]; uint4 q; } pk;
                pk.h[0] = f2bf(a0.x); pk.h[1] = f2bf(a0.y); pk.h[2] = f2bf(a0.z); pk.h[3] = f2bf(a0.w);
                pk.h[4] = f2bf(a1.x); pk.h[5] = f2bf(a1.y); pk.h[6] = f2bf(a1.z); pk.h[7] = f2bf(a1.w);
                *(uint4*)&xa[row * 136 + quad * 32 + cc * 8] = pk.q;
            }
        }
        {
            const int wrow = t >> 1, half = t & 1;
            const unsigned short* wp = wt + (size_t)wrow * 256 + ph * 128 + half * 64;
#pragma unroll
            for (int c = 0; c < 8; ++c)
                *(uint4*)&wb[wrow * 136 + half * 64 + c * 8] = ((const uint4*)wp)[c];
        }
        __syncthreads();

#pragma unroll
        for (int ks = 0; ks < 4; ++ks) {
            const int k0 = ks * 32 + lhi * 8;
            s16x8 afr[4], bfr[2];
#pragma unroll
            for (int mi = 0; mi < 4; ++mi)
                afr[mi] = *(const s16x8*)&xa[(mi * 16 + l15) * 136 + k0];
#pragma unroll
            for (int ni = 0; ni < 2; ++ni)
                bfr[ni] = *(const s16x8*)&wb[(wave * 32 + ni * 16 + l15) * 136 + k0];
#pragma unroll
            for (int mi = 0; mi < 4; ++mi)
#pragma unroll
                for (int ni = 0; ni < 2; ++ni)
                    acc[mi][ni] = __builtin_amdgcn_mfma_f32_16x16x32_bf16(
                        afr[mi], bfr[ni], acc[mi][ni], 0, 0, 0);
        }
        __syncthreads();
    }

    su += __shfl_xor(su, 1); su += __shfl_xor(su, 2);
    sv += __shfl_xor(sv, 1); sv += __shfl_xor(sv, 2);
    if (quad == 0 && valid) { si[gnode] = su; sj[gnode] = sv; }

#pragma unroll
    for (int mi = 0; mi < 4; ++mi) {
        int node = brow + mi * 16 + lhi * 4;
#pragma unroll
        for (int ni = 0; ni < 2; ++ni) {
            int colb = wave * 32 + ni * 16 + l15;
#pragma unroll
            for (int j = 0; j < 4; ++j) {
                if (node + j < N_NODES)
                    psb[(size_t)(node + j) * OUT_DIM + colb] = f2bf(acc[mi][ni][j]);
            }
        }
    }
}

// ---------------- Kernel 2: node degree histogram ----------------
__global__ void khist(const int* __restrict__ row, int* __restrict__ deg) {
    int e = blockIdx.x * 256 + threadIdx.x;
    if (e < N_EDGES) atomicAdd(&deg[row[e]], 1);
}

// ---------------- Kernel 3a/b/c: node-level exclusive scan -> offs ----------------
__global__ void kscan1(const int* __restrict__ deg, int* __restrict__ offs,
                       int* __restrict__ bsum) {
    int i = blockIdx.x * SCAN_B + threadIdx.x;
    int vv = (i < N_NODES) ? deg[i] : 0;
    int lane = threadIdx.x & 63, wid = threadIdx.x >> 6;
    int s = vv;
#pragma unroll
    for (int o = 1; o < 64; o <<= 1) { int tt = __shfl_up(s, o); if (lane >= o) s += tt; }
    __shared__ int wsum[16];
    if (lane == 63) wsum[wid] = s;
    __syncthreads();
    if (threadIdx.x < 16) {
        int tt = wsum[threadIdx.x]; int ss = tt;
#pragma unroll
        for (int o = 1; o < 16; o <<= 1) { int uu = __shfl_up(ss, o); if ((int)threadIdx.x >= o) ss += uu; }
        wsum[threadIdx.x] = ss - tt;
    }
    __syncthreads();
    int excl = s - vv + wsum[wid];
    if (i < N_NODES) offs[i] = excl;
    if (threadIdx.x == SCAN_B - 1) bsum[blockIdx.x] = s + wsum[wid];
}

__global__ void kscan2(const int* __restrict__ bsum, int* __restrict__ boff) {
    int i = threadIdx.x;
    int vv = (i < SCAN_NB) ? bsum[i] : 0;
    int lane = i & 63, wid = i >> 6;
    int s = vv;
#pragma unroll
    for (int o = 1; o < 64; o <<= 1) { int tt = __shfl_up(s, o); if (lane >= o) s += tt; }
    __shared__ int wsum2[2];
    if (lane == 63) wsum2[wid] = s;
    __syncthreads();
    int base = (wid == 1) ? wsum2[0] : 0;
    if (i < SCAN_NB) boff[i] = s - vv + base;
}

__global__ void kscan3(int* __restrict__ offs, const int* __restrict__ boff) {
    int i = blockIdx.x * SCAN_B + threadIdx.x;
    if (i < N_NODES) offs[i] += boff[blockIdx.x];
}

// ------- Kernel 4a: per-(block,bucket) histogram -------
__global__ __launch_bounds__(256) void khist1(const int* __restrict__ row,
                                              int* __restrict__ hist_t) {
    __shared__ int h[NBK];
    const int t = threadIdx.x, blk = blockIdx.x;
    for (int b = t; b < NBK; b += 256) h[b] = 0;
    __syncthreads();
    const int e0 = blk * EPB;
    for (int i = t; i < EPB; i += 256) {
        int r = row[e0 + i];
        atomicAdd(&h[r / BROWS], 1);
    }
    __syncthreads();
    for (int b = t; b < NBK; b += 256)
        hist_t[b * PBLK + blk] = h[b];
}

// ------- Kernel 4b: per-(bucket,block) offsets (bucket base = offs[b*BROWS]) -------
__global__ __launch_bounds__(128) void koff(const int* __restrict__ hist_t,
                                            const int* __restrict__ offs,
                                            int* __restrict__ off) {
    const int b = blockIdx.x, t = threadIdx.x;
    const int lane = t & 63, w = t >> 6;
    int v = hist_t[b * PBLK + t];
    int s = v;
#pragma unroll
    for (int o = 1; o < 64; o <<= 1) { int tt = __shfl_up(s, o); if (lane >= o) s += tt; }
    __shared__ int ws2[2];
    if (lane == 63) ws2[w] = s;
    __syncthreads();
    int base = (w == 1) ? ws2[0] : 0;
    off[b * PBLK + t] = offs[b * BROWS] + base + (s - v);
}

// ------- Kernel 4c: partition edges into bucket-contiguous runs (packed 4B) -------
__global__ __launch_bounds__(256) void kpart1(const int* __restrict__ row,
                                              const int* __restrict__ col,
                                              const int* __restrict__ off,
                                              unsigned int* __restrict__ part) {
    __shared__ int cur[NBK];
    const int t = threadIdx.x, blk = blockIdx.x;
    for (int b = t; b < NBK; b += 256) cur[b] = off[b * PBLK + blk];
    __syncthreads();
    const int e0 = blk * EPB;
    for (int i = t; i < EPB; i += 256) {
        int r = row[e0 + i], c = col[e0 + i];
        int b = r / BROWS;
        int rl = r - b * BROWS;
        int pos = atomicAdd(&cur[b], 1);
        part[pos] = ((unsigned)rl << 17) | (unsigned)c;
    }
}

// ------- Kernel 4d: per-bucket CSR finalize + edge value (L2-local window) -------
__global__ __launch_bounds__(256) void kpart2(const unsigned int* __restrict__ part,
                                              const int* __restrict__ offs,
                                              const float* __restrict__ si,
                                              const float* __restrict__ sj,
                                              const float* __restrict__ dia,
                                              const float* __restrict__ fb,
                                              int2* __restrict__ epack) {
    __shared__ int cur[BROWS];
    __shared__ float sil[BROWS], dial[BROWS];
    const int b = blockIdx.x, t = threadIdx.x;
    const int rbase = b * BROWS;
    if (t < BROWS) {
        cur[t] = offs[rbase + t];
        sil[t] = si[rbase + t];
        dial[t] = dia[rbase + t];
    }
    __syncthreads();
    const int bstart = offs[rbase];
    const int bend = (b == NBK - 1) ? N_EDGES : offs[rbase + BROWS];
    const float fbv = fb[0];
    for (int e = bstart + t; e < bend; e += 256) {
        unsigned pk = part[e];
        int rl = (int)(pk >> 17);
        int c = (int)(pk & 0x1FFFFu);
        float tval = sil[rl] + sj[c] + fbv;
        float sg = 1.f / (1.f + expf(-tval));
        float l2 = log2f(dial[rl] * dia[c]);
        float val = exp2f(-sg * l2);
        int pos = atomicAdd(&cur[rl], 1);
        epack[pos] = make_int2(c, __float_as_int(val));
    }
}

// ------- Kernel 5: per-node gather-accumulate + ReLU (round-4 proven) -------
__global__ __launch_bounds__(256) void kgather(
        const int* __restrict__ offs, const int* __restrict__ deg,
        const int2* __restrict__ epack,
        const unsigned short* __restrict__ psb, float* __restrict__ out) {
    int lane = threadIdx.x & 31;
    int node = blockIdx.x * 8 + (threadIdx.x >> 5);
    if (node >= N_NODES) return;
    int start = offs[node], d = deg[node];
    const int2* ep = epack + start;
    float a0 = 0.f, a1 = 0.f, a2 = 0.f, a3 = 0.f;
    int k = 0;
    for (; k + 2 <= d; k += 2) {
        int2 e0 = ep[k], e1 = ep[k + 1];
        float v0 = __int_as_float(e0.y), v1 = __int_as_float(e1.y);
        ushort4 p0 = *(const ushort4*)&psb[(size_t)e0.x * OUT_DIM + lane * 4];
        ushort4 p1 = *(const ushort4*)&psb[(size_t)e1.x * OUT_DIM + lane * 4];
        a0 = fmaf(v0, bf2f(p0.x), a0); a0 = fmaf(v1, bf2f(p1.x), a0);
        a1 = fmaf(v0, bf2f(p0.y), a1); a1 = fmaf(v1, bf2f(p1.y), a1);
        a2 = fmaf(v0, bf2f(p0.z), a2); a2 = fmaf(v1, bf2f(p1.z), a2);
        a3 = fmaf(v0, bf2f(p0.w), a3); a3 = fmaf(v1, bf2f(p1.w), a3);
    }
    if (k < d) {
        int2 e0 = ep[k];
        float v0 = __int_as_float(e0.y);
        ushort4 p0 = *(const ushort4*)&psb[(size_t)e0.x * OUT_DIM + lane * 4];
        a0 = fmaf(v0, bf2f(p0.x), a0);
        a1 = fmaf(v0, bf2f(p0.y), a1);
        a2 = fmaf(v0, bf2f(p0.z), a2);
        a3 = fmaf(v0, bf2f(p0.w), a3);
    }
    float4 o;
    o.x = fmaxf(a0, 0.f); o.y = fmaxf(a1, 0.f);
    o.z = fmaxf(a2, 0.f); o.w = fmaxf(a3, 0.f);
    *(float4*)&out[(size_t)node * OUT_DIM + lane * 4] = o;
}

extern "C" void kernel_launch(void* const* d_in, const int* in_sizes, int n_in,
                              void* d_out, int out_size, void* d_ws, size_t ws_size,
                              hipStream_t stream) {
    const float* x   = (const float*)d_in[0];
    const float* W   = (const float*)d_in[1];
    const float* fsW = (const float*)d_in[2];
    const float* fw  = (const float*)d_in[3];
    const float* fb  = (const float*)d_in[4];
    const float* dia = (const float*)d_in[5];
    const int*   row = (const int*)d_in[6];
    const int*   col = (const int*)d_in[7];
    float* out = (float*)d_out;

    char* p = (char*)d_ws;
    auto alloc = [&](size_t bytes) -> char* {
        char* r = p; p += (bytes + 255) & ~(size_t)255; return r;
    };
    float* u      = (float*)alloc(256 * 4);
    float* v      = (float*)alloc(256 * 4);
    unsigned short* wtb = (unsigned short*)alloc((size_t)128 * 256 * 2);
    float* si     = (float*)alloc((size_t)N_NODES * 4);
    float* sj     = (float*)alloc((size_t)N_NODES * 4);
    int*   deg    = (int*)alloc((size_t)N_NODES * 4);
    int*   offs   = (int*)alloc((size_t)N_NODES * 4);
    int*   bsum   = (int*)alloc(128 * 4);
    int*   boff   = (int*)alloc(128 * 4);
    unsigned short* psb = (unsigned short*)alloc((size_t)N_NODES * OUT_DIM * 2);
    int*   hist_t = (int*)alloc((size_t)NBK * PBLK * 4);
    int*   off    = (int*)alloc((size_t)NBK * PBLK * 4);
    unsigned int* part = (unsigned int*)alloc((size_t)N_EDGES * 4);
    int2*  epack  = (int2*)alloc((size_t)N_EDGES * 8);

    (void)hipMemsetAsync(deg, 0, (size_t)N_NODES * 4, stream);

    kuv<<<1, 256, 0, stream>>>(fsW, fw, u, v);
    kwt<<<128, 256, 0, stream>>>(W, wtb);
    gemm_mfma<<<(N_NODES + 63) / 64, 256, 0, stream>>>(x, wtb, u, v, psb, si, sj);
    khist<<<N_EDGES / 256, 256, 0, stream>>>(row, deg);
    kscan1<<<SCAN_NB, SCAN_B, 0, stream>>>(deg, offs, bsum);
    kscan2<<<1, 128, 0, stream>>>(bsum, boff);
    kscan3<<<SCAN_NB, SCAN_B, 0, stream>>>(offs, boff);
    khist1<<<PBLK, 256, 0, stream>>>(row, hist_t);
    koff<<<NBK, PBLK, 0, stream>>>(hist_t, offs, off);
    kpart1<<<PBLK, 256, 0, stream>>>(row, col, off, part);
    kpart2<<<NBK, 256, 0, stream>>>(part, offs, si, sj, dia, fb, epack);
    kgather<<<N_NODES / 8, 256, 0, stream>>>(offs, deg, epack, psb, out);
}